// Round 3
// baseline (88527.728 us; speedup 1.0000x reference)
//
#include <hip/hip_runtime.h>

// NeuralCDEDecoder: B=512, T=257, IN=32, H=128, BN=256, OUT=64, K_SUB=4.
// Persistent batch-parallel: 32 WGs x 16 batch rows, whole 256x4x4 RK4 loop
// in-kernel. R3: 1024-thr blocks (4 waves/SIMD for latency hiding), DPP
// row_shr reduce for the contraction (off the LDS pipe), split hi/lo bf16
// z-input for layer 1 + decoder (accuracy). Weights pre-packed into module
// __device__ globals (d_ws corrupted pristine copies in R1 — never again).

using short8   = __attribute__((ext_vector_type(8))) short;
using float4v  = __attribute__((ext_vector_type(4))) float;
using float2v  = __attribute__((ext_vector_type(2))) float;
using ushort2v = __attribute__((ext_vector_type(2))) unsigned short;

__device__ unsigned short g_w1p[32768];
__device__ unsigned short g_w2p[65536];
__device__ unsigned short g_w3p[1048576];
__device__ unsigned short g_mwp[8192];
__device__ unsigned short g_swp[8192];

__device__ __forceinline__ unsigned short* pack_dst(int which){
  switch (which){
    case 0:  return g_w1p;
    case 1:  return g_w2p;
    case 2:  return g_w3p;
    case 3:  return g_mwp;
    default: return g_swp;
  }
}

__device__ __forceinline__ float bf2f(unsigned short h){
  union { unsigned int u; float f; } v; v.u = ((unsigned int)h) << 16; return v.f;
}
__device__ __forceinline__ unsigned short f2bf(float f){
  union { float f; unsigned int u; } v; v.f = f;
  unsigned int u = v.u;
  return (unsigned short)((u + 0x7FFFu + ((u >> 16) & 1u)) >> 16);  // RNE
}
template<bool BF16> __device__ __forceinline__ float loadf(const void* p, long i){
  if constexpr (BF16) return bf2f(((const unsigned short*)p)[i]);
  else                return ((const float*)p)[i];
}
// t[0]=0.0 always; bytes 2..3 are high half of f32 t[0] (=0) or bf16 t[1] (!=0).
__device__ __forceinline__ bool input_is_bf16(const void* t){
  return ((const unsigned short*)t)[1] != 0;
}
__device__ __forceinline__ float tanh_f(float x){
  float e = __builtin_amdgcn_exp2f(x * 2.88539008177793f);          // e^{2x}
  return 1.f - 2.f * __builtin_amdgcn_rcpf(e + 1.f);
}
__device__ __forceinline__ float softplus_f(float x){
  if (x > 20.f) return x;
  float e = __builtin_amdgcn_exp2f(x * 1.44269504088896f);
  return __builtin_amdgcn_logf(1.f + e) * 0.693147180559945f;       // log2->ln
}
// Sum over the 16-lane DPP row; full sum lands in lane 15 of each row.
// VALU-pipe reduce (row_shr DPP), replaces ds_bpermute butterfly.
__device__ __forceinline__ float row_sum16(float v){
  int x;
  x = __builtin_amdgcn_update_dpp(0, __float_as_int(v), 0x118, 0xF, 0xF, true); // row_shr:8
  v += __int_as_float(x);
  x = __builtin_amdgcn_update_dpp(0, __float_as_int(v), 0x114, 0xF, 0xF, true); // row_shr:4
  v += __int_as_float(x);
  x = __builtin_amdgcn_update_dpp(0, __float_as_int(v), 0x112, 0xF, 0xF, true); // row_shr:2
  v += __int_as_float(x);
  x = __builtin_amdgcn_update_dpp(0, __float_as_int(v), 0x111, 0xF, 0xF, true); // row_shr:1
  v += __int_as_float(x);
  return v;
}

// Pack row-major [K,N] weight into fragment order:
// tile (nt,kt) -> 512 bf16 at ((nt*KT+kt)<<9); element (lane,j) = W[kt*32+(lane>>4)*8+j][nt*16+(lane&15)]
template<bool BF16>
__global__ __launch_bounds__(256)
void pack_weight(const void* __restrict__ src, int which,
                 int K, int N, const void* __restrict__ tchk){
  if (input_is_bf16(tchk) != BF16) return;
  unsigned short* dst = pack_dst(which);
  const int KT = K >> 5;
  const long total = (long)(N >> 4) * KT * 512;
  for (long e = (long)blockIdx.x * blockDim.x + threadIdx.x; e < total;
       e += (long)gridDim.x * blockDim.x){
    int  r    = (int)(e & 511);
    long tile = e >> 9;
    int  kt   = (int)(tile % KT);
    int  nt   = (int)(tile / KT);
    int  ln   = r >> 3, j = r & 7;
    int  k    = (kt << 5) + ((ln >> 4) << 3) + j;
    int  n    = (nt << 4) + (ln & 15);
    long si   = (long)k * N + n;
    dst[e] = BF16 ? ((const unsigned short*)src)[si] : f2bf(((const float*)src)[si]);
  }
}

#define STRZ 136   // z buffer row stride (128+8 bf16)
#define STRH 264   // h buffer row stride (256+8 bf16)
#define STRV 132   // vf row stride (fp32)
#define STRD 33    // dxdt row stride (fp32)

template<bool BF16>
__global__ __launch_bounds__(1024, 4)
void cde_main(const void* __restrict__ tin,  const void* __restrict__ z0in,
              const void* __restrict__ Xin,
              const void* __restrict__ b1in, const void* __restrict__ b2in,
              const void* __restrict__ b3in, const void* __restrict__ mbin,
              const void* __restrict__ sbin,
              void* __restrict__ outv)
{
  if (input_is_bf16(tin) != BF16) return;

  const unsigned short* __restrict__ w1p = g_w1p;
  const unsigned short* __restrict__ w2p = g_w2p;
  const unsigned short* __restrict__ w3p = g_w3p;
  const unsigned short* __restrict__ mwp = g_mwp;
  const unsigned short* __restrict__ swp = g_swp;

  __shared__ __align__(16) unsigned short bufZ [16 * STRZ];  // z hi
  __shared__ __align__(16) unsigned short bufZL[16 * STRZ];  // z lo (residual)
  __shared__ __align__(16) unsigned short bufH1[16 * STRH];
  __shared__ __align__(16) unsigned short bufH2[16 * STRH];
  __shared__ __align__(16) float          vfs  [16 * STRV];
  __shared__ __align__(16) float          dxs  [16 * STRD];
  __shared__ __align__(16) float          biasl[4736];       // b1|b2|b3|mb|sb

  const int tid  = threadIdx.x;
  const int lane = tid & 63;
  const int wv   = tid >> 6;        // wave 0..15
  const int c16  = lane & 15;       // MFMA row(A)/col(B,D)
  const int quad = lane >> 4;       // 0..3 (DPP row index)
  const int m0   = blockIdx.x * 16; // batch-row base

  // biases -> LDS (fp32)
  for (int i = tid; i < 4736; i += 1024){
    float v;
    if      (i < 256)  v = loadf<BF16>(b1in, i);
    else if (i < 512)  v = loadf<BF16>(b2in, i - 256);
    else if (i < 4608) v = loadf<BF16>(b3in, i - 512);
    else if (i < 4672) v = loadf<BF16>(mbin, i - 4608);
    else               v = loadf<BF16>(sbin, i - 4672);
    biasl[i] = v;
  }

  // per-thread z-state: thread owns (zm, zd..zd+1)
  const int zm = tid >> 6;          // 16 rows
  const int zd = (tid & 63) << 1;   // 2 dims per thread
  float z[2], zacc[2];
  #pragma unroll
  for (int r = 0; r < 2; ++r) z[r] = loadf<BF16>(z0in, (long)(m0 + zm) * 128 + zd + r);
  {
    ushort2v h, l;
    #pragma unroll
    for (int r = 0; r < 2; ++r){
      h[r] = f2bf(z[r]);
      l[r] = f2bf(z[r] - bf2f(h[r]));
    }
    *(ushort2v*)&bufZ [zm * STRZ + zd] = h;
    *(ushort2v*)&bufZL[zm * STRZ + zd] = l;
  }

  for (int ti = 0; ti < 256; ++ti){
    const float dt = loadf<BF16>(tin, ti + 1) - loadf<BF16>(tin, ti);
    const float hs = dt * 0.25f;                       // RK4 substep h
    if (tid < 512){
      const int m = tid >> 5, i = tid & 31;
      float xc = loadf<BF16>(Xin, ((long)(m0 + m) * 257 + ti    ) * 32 + i);
      float xn = loadf<BF16>(Xin, ((long)(m0 + m) * 257 + ti + 1) * 32 + i);
      dxs[m * STRD + i] = (xn - xc) / dt;
    }
    __syncthreads();                                   // dxs (and initial bufZ/bias) ready
    float dd[2][4];                                    // hoisted dxdt for layer-3 epilogue
    #pragma unroll
    for (int ih = 0; ih < 2; ++ih)
      #pragma unroll
      for (int r = 0; r < 4; ++r)
        dd[ih][r] = dxs[(quad * 4 + r) * STRD + ih * 16 + c16];

    for (int sub = 0; sub < 4; ++sub){
      for (int st = 0; st < 4; ++st){
        __syncthreads();                               // [A] stage input in bufZ/bufZL

        // -------- layer 1: relu(z @ W1 + b1)  K=128 N=256, split hi/lo z
        {
          short8 ah[4], al[4];
          #pragma unroll
          for (int kt = 0; kt < 4; ++kt){
            ah[kt] = *(const short8*)&bufZ [c16 * STRZ + kt * 32 + quad * 8];
            al[kt] = *(const short8*)&bufZL[c16 * STRZ + kt * 32 + quad * 8];
          }
          const int nt = wv;                           // one tile per wave
          const unsigned short* wp = w1p + ((long)(nt * 4) << 9) + lane * 8;
          short8 b[4];
          #pragma unroll
          for (int kt = 0; kt < 4; ++kt) b[kt] = *(const short8*)(wp + (kt << 9));
          float bv = biasl[nt * 16 + c16];
          float4v acc = { bv, bv, bv, bv };
          #pragma unroll
          for (int kt = 0; kt < 4; ++kt)
            acc = __builtin_amdgcn_mfma_f32_16x16x32_bf16(al[kt], b[kt], acc, 0, 0, 0);
          #pragma unroll
          for (int kt = 0; kt < 4; ++kt)
            acc = __builtin_amdgcn_mfma_f32_16x16x32_bf16(ah[kt], b[kt], acc, 0, 0, 0);
          #pragma unroll
          for (int r = 0; r < 4; ++r){
            float v = acc[r] > 0.f ? acc[r] : 0.f;
            bufH1[(quad * 4 + r) * STRH + nt * 16 + c16] = f2bf(v);
          }
        }
        __syncthreads();                               // [B]

        // -------- layer 2: relu(h1 @ W2 + b2)  K=256 N=256
        {
          short8 a[8];
          #pragma unroll
          for (int kt = 0; kt < 8; ++kt)
            a[kt] = *(const short8*)&bufH1[c16 * STRH + kt * 32 + quad * 8];
          const int nt = wv;
          const unsigned short* wp = w2p + ((long)(nt * 8) << 9) + lane * 8;
          short8 b[8];
          #pragma unroll
          for (int kt = 0; kt < 8; ++kt) b[kt] = *(const short8*)(wp + (kt << 9));
          float bv = biasl[256 + nt * 16 + c16];
          float4v acc = { bv, bv, bv, bv };
          #pragma unroll
          for (int kt = 0; kt < 8; ++kt)
            acc = __builtin_amdgcn_mfma_f32_16x16x32_bf16(a[kt], b[kt], acc, 0, 0, 0);
          #pragma unroll
          for (int r = 0; r < 4; ++r){
            float v = acc[r] > 0.f ? acc[r] : 0.f;
            bufH2[(quad * 4 + r) * STRH + nt * 16 + c16] = f2bf(v);
          }
        }
        __syncthreads();                               // [C]

        // -------- layer 3 + contraction: vf = tanh(h2@W3+b3) . dxdt
        // wave w owns ntiles w*16..w*16+15 -> h = w*8..w*8+7
        {
          short8 a[8];
          #pragma unroll
          for (int kt = 0; kt < 8; ++kt)
            a[kt] = *(const short8*)&bufH2[c16 * STRH + kt * 32 + quad * 8];

          const int ntbase = wv * 16;
          short8 bA[8], bB[8];
          {
            const unsigned short* wp = w3p + ((long)(ntbase * 8) << 9) + lane * 8;
            #pragma unroll
            for (int kt = 0; kt < 8; ++kt) bA[kt] = *(const short8*)(wp + (kt << 9));
          }
          float hacc[4];
          #pragma unroll 1
          for (int j = 0; j < 16; j += 2){
            { // prefetch tile j+1
              const unsigned short* wp = w3p + ((long)((ntbase + j + 1) * 8) << 9) + lane * 8;
              #pragma unroll
              for (int kt = 0; kt < 8; ++kt) bB[kt] = *(const short8*)(wp + (kt << 9));
            }
            { // tile j (i-half 0)
              const int nt = ntbase + j;
              float bv = biasl[512 + nt * 16 + c16];
              float4v acc = { bv, bv, bv, bv };
              #pragma unroll
              for (int kt = 0; kt < 8; ++kt)
                acc = __builtin_amdgcn_mfma_f32_16x16x32_bf16(a[kt], bA[kt], acc, 0, 0, 0);
              #pragma unroll
              for (int r = 0; r < 4; ++r)
                hacc[r] = tanh_f(acc[r]) * dd[0][r];
            }
            { // prefetch tile j+2 (clamped; duplicate load is harmless)
              const int jn = (j + 2 < 16) ? (j + 2) : 15;
              const unsigned short* wp = w3p + ((long)((ntbase + jn) * 8) << 9) + lane * 8;
              #pragma unroll
              for (int kt = 0; kt < 8; ++kt) bA[kt] = *(const short8*)(wp + (kt << 9));
            }
            { // tile j+1 (i-half 1) + DPP row-sum + vf write (lane 15 of each quad)
              const int nt = ntbase + j + 1;
              float bv = biasl[512 + nt * 16 + c16];
              float4v acc = { bv, bv, bv, bv };
              #pragma unroll
              for (int kt = 0; kt < 8; ++kt)
                acc = __builtin_amdgcn_mfma_f32_16x16x32_bf16(a[kt], bB[kt], acc, 0, 0, 0);
              const int hidx = (ntbase + j) >> 1;
              float s[4];
              #pragma unroll
              for (int r = 0; r < 4; ++r)
                s[r] = row_sum16(hacc[r] + tanh_f(acc[r]) * dd[1][r]);
              if (c16 == 15){
                #pragma unroll
                for (int r = 0; r < 4; ++r)
                  vfs[(quad * 4 + r) * STRV + hidx] = s[r];
              }
            }
          }
        }
        __syncthreads();                               // [D]

        // -------- RK4 stage combine (registers) + write next stage input
        {
          float2v k = *(const float2v*)&vfs[zm * STRV + zd];
          float nin[2];
          if (st == 0){
            #pragma unroll
            for (int r = 0; r < 2; ++r){
              zacc[r] = z[r] + (hs * (1.f / 6.f)) * k[r];
              nin[r]  = z[r] + 0.5f * hs * k[r];
            }
          } else if (st == 1){
            #pragma unroll
            for (int r = 0; r < 2; ++r){
              zacc[r] += (hs * (1.f / 3.f)) * k[r];
              nin[r]   = z[r] + 0.5f * hs * k[r];
            }
          } else if (st == 2){
            #pragma unroll
            for (int r = 0; r < 2; ++r){
              zacc[r] += (hs * (1.f / 3.f)) * k[r];
              nin[r]   = z[r] + hs * k[r];
            }
          } else {
            #pragma unroll
            for (int r = 0; r < 2; ++r){
              z[r]   = zacc[r] + (hs * (1.f / 6.f)) * k[r];
              nin[r] = z[r];
            }
          }
          ushort2v h, l;
          #pragma unroll
          for (int r = 0; r < 2; ++r){
            h[r] = f2bf(nin[r]);
            l[r] = f2bf(nin[r] - bf2f(h[r]));
          }
          *(ushort2v*)&bufZ [zm * STRZ + zd] = h;
          *(ushort2v*)&bufZL[zm * STRZ + zd] = l;
        }
      } // st
    } // sub

    __syncthreads();                                   // bufZ holds z(t[ti+1])
    // -------- decoder: mean = z@mW+mb ; std = softplus(z@sW+sb)  (waves 0..7)
    if (wv < 8){
      short8 ah[4], al[4];
      #pragma unroll
      for (int kt = 0; kt < 4; ++kt){
        ah[kt] = *(const short8*)&bufZ [c16 * STRZ + kt * 32 + quad * 8];
        al[kt] = *(const short8*)&bufZL[c16 * STRZ + kt * 32 + quad * 8];
      }
      const int  nt    = wv & 3;
      const bool isStd = wv >= 4;
      const unsigned short* wp = (isStd ? swp : mwp) + ((long)(nt * 4) << 9) + lane * 8;
      short8 b[4];
      #pragma unroll
      for (int kt = 0; kt < 4; ++kt) b[kt] = *(const short8*)(wp + (kt << 9));
      float bv = biasl[(isStd ? 4672 : 4608) + nt * 16 + c16];
      float4v acc = { bv, bv, bv, bv };
      #pragma unroll
      for (int kt = 0; kt < 4; ++kt)
        acc = __builtin_amdgcn_mfma_f32_16x16x32_bf16(al[kt], b[kt], acc, 0, 0, 0);
      #pragma unroll
      for (int kt = 0; kt < 4; ++kt)
        acc = __builtin_amdgcn_mfma_f32_16x16x32_bf16(ah[kt], b[kt], acc, 0, 0, 0);
      const long obase = isStd ? 8388608L : 0L;        // B*(T-1)*OUT
      #pragma unroll
      for (int r = 0; r < 4; ++r){
        float v = acc[r];
        if (isStd) v = softplus_f(v);
        long oi = obase + ((long)(m0 + quad * 4 + r) * 256 + ti) * 64 + nt * 16 + c16;
        if constexpr (BF16) ((unsigned short*)outv)[oi] = f2bf(v);
        else                ((float*)outv)[oi] = v;
      }
    }
  } // ti
}

extern "C" void kernel_launch(void* const* d_in, const int* in_sizes, int n_in,
                              void* d_out, int out_size, void* d_ws, size_t ws_size,
                              hipStream_t stream)
{
  const void* t  = d_in[0];
  const void* z0 = d_in[1];
  const void* X  = d_in[2];
  const void* W1 = d_in[3];
  const void* b1 = d_in[4];
  const void* W2 = d_in[5];
  const void* b2 = d_in[6];
  const void* W3 = d_in[7];
  const void* b3 = d_in[8];
  const void* mW = d_in[9];
  const void* mb = d_in[10];
  const void* sW = d_in[11];
  const void* sb = d_in[12];

  // Both dtype variants launched; each checks input dtype and the
  // non-matching one returns immediately (t[0]==0.0 discriminator).
  pack_weight<true ><<<256, 256, 0, stream>>>(W1, 0, 128,  256, t);
  pack_weight<true ><<<256, 256, 0, stream>>>(W2, 1, 256,  256, t);
  pack_weight<true ><<<512, 256, 0, stream>>>(W3, 2, 256, 4096, t);
  pack_weight<true ><<< 64, 256, 0, stream>>>(mW, 3, 128,   64, t);
  pack_weight<true ><<< 64, 256, 0, stream>>>(sW, 4, 128,   64, t);
  pack_weight<false><<<256, 256, 0, stream>>>(W1, 0, 128,  256, t);
  pack_weight<false><<<256, 256, 0, stream>>>(W2, 1, 256,  256, t);
  pack_weight<false><<<512, 256, 0, stream>>>(W3, 2, 256, 4096, t);
  pack_weight<false><<< 64, 256, 0, stream>>>(mW, 3, 128,   64, t);
  pack_weight<false><<< 64, 256, 0, stream>>>(sW, 4, 128,   64, t);

  cde_main<true ><<<32, 1024, 0, stream>>>(t, z0, X, b1, b2, b3, mb, sb, d_out);
  cde_main<false><<<32, 1024, 0, stream>>>(t, z0, X, b1, b2, b3, mb, sb, d_out);
  (void)in_sizes; (void)n_in; (void)out_size; (void)d_ws; (void)ws_size;
}

// Round 4
// 71942.407 us; speedup vs baseline: 1.2305x; 1.2305x over previous
//
#include <hip/hip_runtime.h>

// NeuralCDEDecoder: B=512, T=257, IN=32, H=128, BN=256, OUT=64, K_SUB=4.
// R4: 64 blocks x 1024 threads, 8 batch rows/block. Hi/lo bf16 residual
// pairs interleaved into the 16 MFMA A-rows (even=hi, odd=lo) -> near-fp32
// activations at zero extra MFMA cost; pair-sum is register-local.
// Single-buffered layer-3 B-frags (R3 double-buffer spilled at the 128-VGPR
// cap -> 2.4GB scratch writes). Weights packed in module __device__ globals.

using short8   = __attribute__((ext_vector_type(8))) short;
using float4v  = __attribute__((ext_vector_type(4))) float;

__device__ unsigned short g_w1p[32768];
__device__ unsigned short g_w2p[65536];
__device__ unsigned short g_w3p[1048576];
__device__ unsigned short g_mwp[8192];
__device__ unsigned short g_swp[8192];

__device__ __forceinline__ unsigned short* pack_dst(int which){
  switch (which){
    case 0:  return g_w1p;
    case 1:  return g_w2p;
    case 2:  return g_w3p;
    case 3:  return g_mwp;
    default: return g_swp;
  }
}

__device__ __forceinline__ float bf2f(unsigned short h){
  union { unsigned int u; float f; } v; v.u = ((unsigned int)h) << 16; return v.f;
}
__device__ __forceinline__ unsigned short f2bf(float f){
  union { float f; unsigned int u; } v; v.f = f;
  unsigned int u = v.u;
  return (unsigned short)((u + 0x7FFFu + ((u >> 16) & 1u)) >> 16);  // RNE
}
template<bool BF16> __device__ __forceinline__ float loadf(const void* p, long i){
  if constexpr (BF16) return bf2f(((const unsigned short*)p)[i]);
  else                return ((const float*)p)[i];
}
// t[0]=0.0 always; bytes 2..3 are high half of f32 t[0] (=0) or bf16 t[1] (!=0).
__device__ __forceinline__ bool input_is_bf16(const void* t){
  return ((const unsigned short*)t)[1] != 0;
}
__device__ __forceinline__ float tanh_f(float x){
  float e = __builtin_amdgcn_exp2f(x * 2.88539008177793f);          // e^{2x}
  return 1.f - 2.f * __builtin_amdgcn_rcpf(e + 1.f);
}
__device__ __forceinline__ float softplus_f(float x){
  if (x > 20.f) return x;
  float e = __builtin_amdgcn_exp2f(x * 1.44269504088896f);
  return __builtin_amdgcn_logf(1.f + e) * 0.693147180559945f;       // log2->ln
}
// Sum across each 16-lane row; full sum lands in lane 15 of the row (VALU DPP).
__device__ __forceinline__ float row_sum16(float v){
  int x;
  x = __builtin_amdgcn_update_dpp(0, __float_as_int(v), 0x118, 0xF, 0xF, true); // row_shr:8
  v += __int_as_float(x);
  x = __builtin_amdgcn_update_dpp(0, __float_as_int(v), 0x114, 0xF, 0xF, true); // row_shr:4
  v += __int_as_float(x);
  x = __builtin_amdgcn_update_dpp(0, __float_as_int(v), 0x112, 0xF, 0xF, true); // row_shr:2
  v += __int_as_float(x);
  x = __builtin_amdgcn_update_dpp(0, __float_as_int(v), 0x111, 0xF, 0xF, true); // row_shr:1
  v += __int_as_float(x);
  return v;
}

// Pack row-major [K,N] weight into fragment order:
// tile (nt,kt) -> 512 bf16 at ((nt*KT+kt)<<9); elem (lane,j) = W[kt*32+(lane>>4)*8+j][nt*16+(lane&15)]
template<bool BF16>
__global__ __launch_bounds__(256)
void pack_weight(const void* __restrict__ src, int which,
                 int K, int N, const void* __restrict__ tchk){
  if (input_is_bf16(tchk) != BF16) return;
  unsigned short* dst = pack_dst(which);
  const int KT = K >> 5;
  const long total = (long)(N >> 4) * KT * 512;
  for (long e = (long)blockIdx.x * blockDim.x + threadIdx.x; e < total;
       e += (long)gridDim.x * blockDim.x){
    int  r    = (int)(e & 511);
    long tile = e >> 9;
    int  kt   = (int)(tile % KT);
    int  nt   = (int)(tile / KT);
    int  ln   = r >> 3, j = r & 7;
    int  k    = (kt << 5) + ((ln >> 4) << 3) + j;
    int  n    = (nt << 4) + (ln & 15);
    long si   = (long)k * N + n;
    dst[e] = BF16 ? ((const unsigned short*)src)[si] : f2bf(((const float*)src)[si]);
  }
}

#define STRZ 136   // z buffer row stride (bf16), 16 rows = hi/lo x 8 batch rows
#define STRH 264   // h buffer row stride (bf16), 16 rows = hi/lo x 8
#define STRV 132   // vf row stride (fp32), 8 rows
#define STRD 33    // dxdt row stride (fp32), 8 rows

template<bool BF16>
__global__ __launch_bounds__(1024)
void cde_main(const void* __restrict__ tin,  const void* __restrict__ z0in,
              const void* __restrict__ Xin,
              const void* __restrict__ b1in, const void* __restrict__ b2in,
              const void* __restrict__ b3in, const void* __restrict__ mbin,
              const void* __restrict__ sbin,
              void* __restrict__ outv)
{
  if (input_is_bf16(tin) != BF16) return;

  const unsigned short* __restrict__ w1p = g_w1p;
  const unsigned short* __restrict__ w2p = g_w2p;
  const unsigned short* __restrict__ w3p = g_w3p;
  const unsigned short* __restrict__ mwp = g_mwp;
  const unsigned short* __restrict__ swp = g_swp;

  __shared__ __align__(16) unsigned short bufZ [16 * STRZ];
  __shared__ __align__(16) unsigned short bufH1[16 * STRH];
  __shared__ __align__(16) unsigned short bufH2[16 * STRH];
  __shared__ __align__(16) float          vfs  [ 8 * STRV];
  __shared__ __align__(16) float          dxs  [ 8 * STRD];
  __shared__ __align__(16) float          biasl[4736];       // b1|b2|b3|mb|sb

  const int tid  = threadIdx.x;
  const int lane = tid & 63;
  const int wv   = tid >> 6;        // wave 0..15
  const int c16  = lane & 15;       // MFMA A-row / B,D-col
  const int quad = lane >> 4;       // 0..3
  const int m0   = blockIdx.x * 8;  // batch-row base (8 rows per block)

  // biases -> LDS (fp32)
  for (int i = tid; i < 4736; i += 1024){
    float v;
    if      (i < 256)  v = loadf<BF16>(b1in, i);
    else if (i < 512)  v = loadf<BF16>(b2in, i - 256);
    else if (i < 4608) v = loadf<BF16>(b3in, i - 512);
    else if (i < 4672) v = loadf<BF16>(mbin, i - 4608);
    else               v = loadf<BF16>(sbin, i - 4672);
    biasl[i] = v;
  }

  // per-thread z-state: thread owns dim zd of batch sub-row zm (1 value)
  const int zm = tid >> 7;          // 0..7
  const int zd = tid & 127;         // 0..127
  float z = loadf<BF16>(z0in, (long)(m0 + zm) * 128 + zd);
  float zacc = 0.f;
  {
    unsigned short h = f2bf(z);
    bufZ[(2 * zm    ) * STRZ + zd] = h;
    bufZ[(2 * zm + 1) * STRZ + zd] = f2bf(z - bf2f(h));
  }

  for (int ti = 0; ti < 256; ++ti){
    const float dt = loadf<BF16>(tin, ti + 1) - loadf<BF16>(tin, ti);
    const float hs = dt * 0.25f;                       // RK4 substep h
    if (tid < 256){
      const int m = tid >> 5, i = tid & 31;
      float xc = loadf<BF16>(Xin, ((long)(m0 + m) * 257 + ti    ) * 32 + i);
      float xn = loadf<BF16>(Xin, ((long)(m0 + m) * 257 + ti + 1) * 32 + i);
      dxs[m * STRD + i] = (xn - xc) / dt;
    }
    __syncthreads();                                   // dxs (and bufZ/bias) ready
    // dd[ih][s] = dxdt[m = quad*2+s][i = ih*16 + c16]
    float dd[2][2];
    #pragma unroll
    for (int ih = 0; ih < 2; ++ih)
      #pragma unroll
      for (int s = 0; s < 2; ++s)
        dd[ih][s] = dxs[(quad * 2 + s) * STRD + ih * 16 + c16];

    for (int sub = 0; sub < 4; ++sub){
      for (int st = 0; st < 4; ++st){
        __syncthreads();                               // [A] stage input in bufZ

        // -------- layer 1: relu(z @ W1 + b1)  K=128 N=256 (1 ntile/wave)
        {
          short8 a[4];
          #pragma unroll
          for (int kt = 0; kt < 4; ++kt)
            a[kt] = *(const short8*)&bufZ[c16 * STRZ + kt * 32 + quad * 8];
          const int nt = wv;
          const unsigned short* wp = w1p + ((long)(nt * 4) << 9) + lane * 8;
          short8 b[4];
          #pragma unroll
          for (int kt = 0; kt < 4; ++kt) b[kt] = *(const short8*)(wp + (kt << 9));
          float4v acc = { 0.f, 0.f, 0.f, 0.f };
          #pragma unroll
          for (int kt = 0; kt < 4; ++kt)
            acc = __builtin_amdgcn_mfma_f32_16x16x32_bf16(a[kt], b[kt], acc, 0, 0, 0);
          const float bv = biasl[nt * 16 + c16];
          #pragma unroll
          for (int s = 0; s < 2; ++s){
            float v = acc[2 * s] + acc[2 * s + 1] + bv;
            v = v > 0.f ? v : 0.f;
            unsigned short h = f2bf(v);
            const int row = quad * 4 + 2 * s;
            bufH1[ row      * STRH + nt * 16 + c16] = h;
            bufH1[(row + 1) * STRH + nt * 16 + c16] = f2bf(v - bf2f(h));
          }
        }
        __syncthreads();                               // [B]

        // -------- layer 2: relu(h1 @ W2 + b2)  K=256 N=256 (1 ntile/wave)
        {
          short8 a[8];
          #pragma unroll
          for (int kt = 0; kt < 8; ++kt)
            a[kt] = *(const short8*)&bufH1[c16 * STRH + kt * 32 + quad * 8];
          const int nt = wv;
          const unsigned short* wp = w2p + ((long)(nt * 8) << 9) + lane * 8;
          short8 b[8];
          #pragma unroll
          for (int kt = 0; kt < 8; ++kt) b[kt] = *(const short8*)(wp + (kt << 9));
          float4v acc = { 0.f, 0.f, 0.f, 0.f };
          #pragma unroll
          for (int kt = 0; kt < 8; ++kt)
            acc = __builtin_amdgcn_mfma_f32_16x16x32_bf16(a[kt], b[kt], acc, 0, 0, 0);
          const float bv = biasl[256 + nt * 16 + c16];
          #pragma unroll
          for (int s = 0; s < 2; ++s){
            float v = acc[2 * s] + acc[2 * s + 1] + bv;
            v = v > 0.f ? v : 0.f;
            unsigned short h = f2bf(v);
            const int row = quad * 4 + 2 * s;
            bufH2[ row      * STRH + nt * 16 + c16] = h;
            bufH2[(row + 1) * STRH + nt * 16 + c16] = f2bf(v - bf2f(h));
          }
        }
        __syncthreads();                               // [C]

        // -------- layer 3 + contraction: vf = tanh(h2@W3+b3) . dxdt
        // wave owns ntiles wv*16 .. wv*16+15 -> h indices wv*8 .. wv*8+7
        {
          short8 a[8];
          #pragma unroll
          for (int kt = 0; kt < 8; ++kt)
            a[kt] = *(const short8*)&bufH2[c16 * STRH + kt * 32 + quad * 8];

          const int ntbase = wv * 16;
          #pragma unroll 1
          for (int j = 0; j < 16; j += 2){
            float t0[2], t1[2];
            { // tile j: i in [0,16)
              const int nt = ntbase + j;
              const unsigned short* wp = w3p + ((long)(nt * 8) << 9) + lane * 8;
              short8 b[8];
              #pragma unroll
              for (int kt = 0; kt < 8; ++kt) b[kt] = *(const short8*)(wp + (kt << 9));
              float4v acc = { 0.f, 0.f, 0.f, 0.f };
              #pragma unroll
              for (int kt = 0; kt < 8; ++kt)
                acc = __builtin_amdgcn_mfma_f32_16x16x32_bf16(a[kt], b[kt], acc, 0, 0, 0);
              const float bv = biasl[512 + nt * 16 + c16];
              #pragma unroll
              for (int s = 0; s < 2; ++s)
                t0[s] = tanh_f(acc[2 * s] + acc[2 * s + 1] + bv) * dd[0][s];
            }
            { // tile j+1: i in [16,32) + reduce + vf write
              const int nt = ntbase + j + 1;
              const unsigned short* wp = w3p + ((long)(nt * 8) << 9) + lane * 8;
              short8 b[8];
              #pragma unroll
              for (int kt = 0; kt < 8; ++kt) b[kt] = *(const short8*)(wp + (kt << 9));
              float4v acc = { 0.f, 0.f, 0.f, 0.f };
              #pragma unroll
              for (int kt = 0; kt < 8; ++kt)
                acc = __builtin_amdgcn_mfma_f32_16x16x32_bf16(a[kt], b[kt], acc, 0, 0, 0);
              const float bv = biasl[512 + nt * 16 + c16];
              #pragma unroll
              for (int s = 0; s < 2; ++s)
                t1[s] = tanh_f(acc[2 * s] + acc[2 * s + 1] + bv) * dd[1][s];
              const int hidx = (ntbase + j) >> 1;
              #pragma unroll
              for (int s = 0; s < 2; ++s){
                float r = row_sum16(t0[s] + t1[s]);
                if (c16 == 15) vfs[(quad * 2 + s) * STRV + hidx] = r;
              }
            }
          }
        }
        __syncthreads();                               // [D]

        // -------- RK4 stage combine (registers) + write next stage input
        {
          const float k = vfs[zm * STRV + zd];
          float nin;
          if (st == 0){
            zacc = z + (hs * (1.f / 6.f)) * k;
            nin  = z + 0.5f * hs * k;
          } else if (st == 1){
            zacc += (hs * (1.f / 3.f)) * k;
            nin   = z + 0.5f * hs * k;
          } else if (st == 2){
            zacc += (hs * (1.f / 3.f)) * k;
            nin   = z + hs * k;
          } else {
            z    = zacc + (hs * (1.f / 6.f)) * k;
            nin  = z;
          }
          unsigned short h = f2bf(nin);
          bufZ[(2 * zm    ) * STRZ + zd] = h;
          bufZ[(2 * zm + 1) * STRZ + zd] = f2bf(nin - bf2f(h));
        }
      } // st
    } // sub

    __syncthreads();                                   // bufZ holds z(t[ti+1])
    // -------- decoder: mean = z@mW+mb ; std = softplus(z@sW+sb)  (waves 0..7)
    if (wv < 8){
      short8 a[4];
      #pragma unroll
      for (int kt = 0; kt < 4; ++kt)
        a[kt] = *(const short8*)&bufZ[c16 * STRZ + kt * 32 + quad * 8];
      const int  nt    = wv & 3;
      const bool isStd = wv >= 4;
      const unsigned short* wp = (isStd ? swp : mwp) + ((long)(nt * 4) << 9) + lane * 8;
      short8 b[4];
      #pragma unroll
      for (int kt = 0; kt < 4; ++kt) b[kt] = *(const short8*)(wp + (kt << 9));
      float4v acc = { 0.f, 0.f, 0.f, 0.f };
      #pragma unroll
      for (int kt = 0; kt < 4; ++kt)
        acc = __builtin_amdgcn_mfma_f32_16x16x32_bf16(a[kt], b[kt], acc, 0, 0, 0);
      const float bv    = biasl[(isStd ? 4672 : 4608) + nt * 16 + c16];
      const long  obase = isStd ? 8388608L : 0L;       // B*(T-1)*OUT
      #pragma unroll
      for (int s = 0; s < 2; ++s){
        float v = acc[2 * s] + acc[2 * s + 1] + bv;
        if (isStd) v = softplus_f(v);
        long oi = obase + ((long)(m0 + quad * 2 + s) * 256 + ti) * 64 + nt * 16 + c16;
        if constexpr (BF16) ((unsigned short*)outv)[oi] = f2bf(v);
        else                ((float*)outv)[oi] = v;
      }
    }
  } // ti
}

extern "C" void kernel_launch(void* const* d_in, const int* in_sizes, int n_in,
                              void* d_out, int out_size, void* d_ws, size_t ws_size,
                              hipStream_t stream)
{
  const void* t  = d_in[0];
  const void* z0 = d_in[1];
  const void* X  = d_in[2];
  const void* W1 = d_in[3];
  const void* b1 = d_in[4];
  const void* W2 = d_in[5];
  const void* b2 = d_in[6];
  const void* W3 = d_in[7];
  const void* b3 = d_in[8];
  const void* mW = d_in[9];
  const void* mb = d_in[10];
  const void* sW = d_in[11];
  const void* sb = d_in[12];

  // Both dtype variants launched; each checks input dtype and the
  // non-matching one returns immediately (t[0]==0.0 discriminator).
  pack_weight<true ><<<256, 256, 0, stream>>>(W1, 0, 128,  256, t);
  pack_weight<true ><<<256, 256, 0, stream>>>(W2, 1, 256,  256, t);
  pack_weight<true ><<<512, 256, 0, stream>>>(W3, 2, 256, 4096, t);
  pack_weight<true ><<< 64, 256, 0, stream>>>(mW, 3, 128,   64, t);
  pack_weight<true ><<< 64, 256, 0, stream>>>(sW, 4, 128,   64, t);
  pack_weight<false><<<256, 256, 0, stream>>>(W1, 0, 128,  256, t);
  pack_weight<false><<<256, 256, 0, stream>>>(W2, 1, 256,  256, t);
  pack_weight<false><<<512, 256, 0, stream>>>(W3, 2, 256, 4096, t);
  pack_weight<false><<< 64, 256, 0, stream>>>(mW, 3, 128,   64, t);
  pack_weight<false><<< 64, 256, 0, stream>>>(sW, 4, 128,   64, t);

  cde_main<true ><<<64, 1024, 0, stream>>>(t, z0, X, b1, b2, b3, mb, sb, d_out);
  cde_main<false><<<64, 1024, 0, stream>>>(t, z0, X, b1, b2, b3, mb, sb, d_out);
  (void)in_sizes; (void)n_in; (void)out_size; (void)d_ws; (void)ws_size;
}

// Round 5
// 55754.211 us; speedup vs baseline: 1.5878x; 1.2903x over previous
//
#include <hip/hip_runtime.h>

// NeuralCDEDecoder: B=512, T=257, IN=32, H=128, BN=256, OUT=64, K_SUB=4.
// R5: h-split. 128 blocks = 64 row-groups x 2 halves. Each half-block:
// full L1+L2 (192KB/stage), half of W3 (1MB/stage) -> per-CU L2 stream
// 2.24->1.22MB/stage (R4 was at ~90% of the ~150GB/s per-CU L2 port).
// Halves exchange their z-slice (fp32-exact, 2KB) per stage via sc1
// agent-scope atomics + monotone flag, parity double-buffered.
// Weights packed in module __device__ globals; flags reset by a tiny
// stream-ordered kernel each call. fp32 state, hi/lo bf16 activations.

using short8   = __attribute__((ext_vector_type(8))) short;
using float4v  = __attribute__((ext_vector_type(4))) float;

__device__ unsigned short g_w1p[32768];
__device__ unsigned short g_w2p[65536];
__device__ unsigned short g_w3p[1048576];
__device__ unsigned short g_mwp[8192];
__device__ unsigned short g_swp[8192];

__device__ int   g_flag[128];                 // last stage posted per block
__device__ float g_zx[2 * 64 * 2 * 512];      // [parity][group][half][8rows*64dims]

__global__ void reset_flags(){
  if (threadIdx.x < 128) g_flag[threadIdx.x] = -1;
}

__device__ __forceinline__ unsigned short* pack_dst(int which){
  switch (which){
    case 0:  return g_w1p;
    case 1:  return g_w2p;
    case 2:  return g_w3p;
    case 3:  return g_mwp;
    default: return g_swp;
  }
}

__device__ __forceinline__ float bf2f(unsigned short h){
  union { unsigned int u; float f; } v; v.u = ((unsigned int)h) << 16; return v.f;
}
__device__ __forceinline__ unsigned short f2bf(float f){
  union { float f; unsigned int u; } v; v.f = f;
  unsigned int u = v.u;
  return (unsigned short)((u + 0x7FFFu + ((u >> 16) & 1u)) >> 16);  // RNE
}
template<bool BF16> __device__ __forceinline__ float loadf(const void* p, long i){
  if constexpr (BF16) return bf2f(((const unsigned short*)p)[i]);
  else                return ((const float*)p)[i];
}
// t[0]=0.0 always; bytes 2..3 are high half of f32 t[0] (=0) or bf16 t[1] (!=0).
__device__ __forceinline__ bool input_is_bf16(const void* t){
  return ((const unsigned short*)t)[1] != 0;
}
__device__ __forceinline__ float tanh_f(float x){
  float e = __builtin_amdgcn_exp2f(x * 2.88539008177793f);          // e^{2x}
  return 1.f - 2.f * __builtin_amdgcn_rcpf(e + 1.f);
}
__device__ __forceinline__ float softplus_f(float x){
  if (x > 20.f) return x;
  float e = __builtin_amdgcn_exp2f(x * 1.44269504088896f);
  return __builtin_amdgcn_logf(1.f + e) * 0.693147180559945f;       // log2->ln
}
// Sum across each 16-lane row; full sum lands in lane 15 of the row (VALU DPP).
__device__ __forceinline__ float row_sum16(float v){
  int x;
  x = __builtin_amdgcn_update_dpp(0, __float_as_int(v), 0x118, 0xF, 0xF, true); // row_shr:8
  v += __int_as_float(x);
  x = __builtin_amdgcn_update_dpp(0, __float_as_int(v), 0x114, 0xF, 0xF, true); // row_shr:4
  v += __int_as_float(x);
  x = __builtin_amdgcn_update_dpp(0, __float_as_int(v), 0x112, 0xF, 0xF, true); // row_shr:2
  v += __int_as_float(x);
  x = __builtin_amdgcn_update_dpp(0, __float_as_int(v), 0x111, 0xF, 0xF, true); // row_shr:1
  v += __int_as_float(x);
  return v;
}

// Pack row-major [K,N] weight into fragment order:
// tile (nt,kt) -> 512 bf16 at ((nt*KT+kt)<<9); elem (lane,j) = W[kt*32+(lane>>4)*8+j][nt*16+(lane&15)]
template<bool BF16>
__global__ __launch_bounds__(256)
void pack_weight(const void* __restrict__ src, int which,
                 int K, int N, const void* __restrict__ tchk){
  if (input_is_bf16(tchk) != BF16) return;
  unsigned short* dst = pack_dst(which);
  const int KT = K >> 5;
  const long total = (long)(N >> 4) * KT * 512;
  for (long e = (long)blockIdx.x * blockDim.x + threadIdx.x; e < total;
       e += (long)gridDim.x * blockDim.x){
    int  r    = (int)(e & 511);
    long tile = e >> 9;
    int  kt   = (int)(tile % KT);
    int  nt   = (int)(tile / KT);
    int  ln   = r >> 3, j = r & 7;
    int  k    = (kt << 5) + ((ln >> 4) << 3) + j;
    int  n    = (nt << 4) + (ln & 15);
    long si   = (long)k * N + n;
    dst[e] = BF16 ? ((const unsigned short*)src)[si] : f2bf(((const float*)src)[si]);
  }
}

#define STRZ 136   // z buffer row stride (bf16), 16 rows = hi/lo x 8 batch rows
#define STRH 264   // h buffer row stride (bf16), 16 rows = hi/lo x 8
#define STRV 132   // vf row stride (fp32), 8 rows
#define STRD 33    // dxdt row stride (fp32), 8 rows

template<bool BF16>
__global__ __launch_bounds__(1024)
void cde_main(const void* __restrict__ tin,  const void* __restrict__ z0in,
              const void* __restrict__ Xin,
              const void* __restrict__ b1in, const void* __restrict__ b2in,
              const void* __restrict__ b3in, const void* __restrict__ mbin,
              const void* __restrict__ sbin,
              void* __restrict__ outv)
{
  if (input_is_bf16(tin) != BF16) return;

  const unsigned short* __restrict__ w1p = g_w1p;
  const unsigned short* __restrict__ w2p = g_w2p;
  const unsigned short* __restrict__ w3p = g_w3p;
  const unsigned short* __restrict__ mwp = g_mwp;
  const unsigned short* __restrict__ swp = g_swp;

  __shared__ __align__(16) unsigned short bufZ [16 * STRZ];
  __shared__ __align__(16) unsigned short bufH1[16 * STRH];
  __shared__ __align__(16) unsigned short bufH2[16 * STRH];
  __shared__ __align__(16) float          vfs  [ 8 * STRV];
  __shared__ __align__(16) float          dxs  [ 8 * STRD];
  __shared__ __align__(16) float          biasl[4736];       // b1|b2|b3|mb|sb

  const int tid  = threadIdx.x;
  const int lane = tid & 63;
  const int wv   = tid >> 6;          // wave 0..15
  const int c16  = lane & 15;         // MFMA A-row / B,D-col
  const int quad = lane >> 4;         // 0..3
  const int hb   = blockIdx.x & 1;    // h-half: 0 -> h<64, 1 -> h>=64
  const int grp  = blockIdx.x >> 1;   // row group 0..63
  const int prt  = blockIdx.x ^ 1;    // partner block
  const int m0   = grp * 8;           // batch-row base (8 rows per group)

  // biases -> LDS (fp32)
  for (int i = tid; i < 4736; i += 1024){
    float v;
    if      (i < 256)  v = loadf<BF16>(b1in, i);
    else if (i < 512)  v = loadf<BF16>(b2in, i - 256);
    else if (i < 4608) v = loadf<BF16>(b3in, i - 512);
    else if (i < 4672) v = loadf<BF16>(mbin, i - 4608);
    else               v = loadf<BF16>(sbin, i - 4672);
    biasl[i] = v;
  }

  // per-thread z-state: thread owns dim zd of batch sub-row zm.
  // Threads whose zd falls in this block's h-half do the RK4 update and
  // publish; the other 512 threads receive the partner's slice.
  const int  zm   = tid >> 7;         // 0..7
  const int  zd   = tid & 127;        // 0..127
  const bool own  = (zd >> 6) == hb;
  const int  xidx = zm * 64 + (zd & 63);
  float z = loadf<BF16>(z0in, (long)(m0 + zm) * 128 + zd);
  float zacc = 0.f;
  {
    unsigned short h = f2bf(z);
    bufZ[(2 * zm    ) * STRZ + zd] = h;
    bufZ[(2 * zm + 1) * STRZ + zd] = f2bf(z - bf2f(h));
  }

  for (int ti = 0; ti < 256; ++ti){
    const float dt = loadf<BF16>(tin, ti + 1) - loadf<BF16>(tin, ti);
    const float hs = dt * 0.25f;                       // RK4 substep h
    if (tid < 256){
      const int m = tid >> 5, i = tid & 31;
      float xc = loadf<BF16>(Xin, ((long)(m0 + m) * 257 + ti    ) * 32 + i);
      float xn = loadf<BF16>(Xin, ((long)(m0 + m) * 257 + ti + 1) * 32 + i);
      dxs[m * STRD + i] = (xn - xc) / dt;
    }
    __syncthreads();                                   // dxs (and bufZ/bias) ready
    // dd[ih][s] = dxdt[m = quad*2+s][i = ih*16 + c16]
    float dd[2][2];
    #pragma unroll
    for (int ih = 0; ih < 2; ++ih)
      #pragma unroll
      for (int s = 0; s < 2; ++s)
        dd[ih][s] = dxs[(quad * 2 + s) * STRD + ih * 16 + c16];

    for (int sub = 0; sub < 4; ++sub){
      for (int st = 0; st < 4; ++st){
        const int stg = (ti << 4) + (sub << 2) + st;   // global stage 0..4095
        const int par = stg & 1;
        __syncthreads();                               // [A] stage input in bufZ

        // -------- layer 1: relu(z @ W1 + b1)  K=128 N=256 (1 ntile/wave)
        {
          short8 a[4];
          #pragma unroll
          for (int kt = 0; kt < 4; ++kt)
            a[kt] = *(const short8*)&bufZ[c16 * STRZ + kt * 32 + quad * 8];
          const int nt = wv;
          const unsigned short* wp = w1p + ((long)(nt * 4) << 9) + lane * 8;
          short8 b[4];
          #pragma unroll
          for (int kt = 0; kt < 4; ++kt) b[kt] = *(const short8*)(wp + (kt << 9));
          float4v acc = { 0.f, 0.f, 0.f, 0.f };
          #pragma unroll
          for (int kt = 0; kt < 4; ++kt)
            acc = __builtin_amdgcn_mfma_f32_16x16x32_bf16(a[kt], b[kt], acc, 0, 0, 0);
          const float bv = biasl[nt * 16 + c16];
          #pragma unroll
          for (int s = 0; s < 2; ++s){
            float v = acc[2 * s] + acc[2 * s + 1] + bv;
            v = v > 0.f ? v : 0.f;
            unsigned short h = f2bf(v);
            const int row = quad * 4 + 2 * s;
            bufH1[ row      * STRH + nt * 16 + c16] = h;
            bufH1[(row + 1) * STRH + nt * 16 + c16] = f2bf(v - bf2f(h));
          }
        }
        __syncthreads();                               // [B]

        // -------- layer 2: relu(h1 @ W2 + b2)  K=256 N=256 (1 ntile/wave)
        {
          short8 a[8];
          #pragma unroll
          for (int kt = 0; kt < 8; ++kt)
            a[kt] = *(const short8*)&bufH1[c16 * STRH + kt * 32 + quad * 8];
          const int nt = wv;
          const unsigned short* wp = w2p + ((long)(nt * 8) << 9) + lane * 8;
          short8 b[8];
          #pragma unroll
          for (int kt = 0; kt < 8; ++kt) b[kt] = *(const short8*)(wp + (kt << 9));
          float4v acc = { 0.f, 0.f, 0.f, 0.f };
          #pragma unroll
          for (int kt = 0; kt < 8; ++kt)
            acc = __builtin_amdgcn_mfma_f32_16x16x32_bf16(a[kt], b[kt], acc, 0, 0, 0);
          const float bv = biasl[256 + nt * 16 + c16];
          #pragma unroll
          for (int s = 0; s < 2; ++s){
            float v = acc[2 * s] + acc[2 * s + 1] + bv;
            v = v > 0.f ? v : 0.f;
            unsigned short h = f2bf(v);
            const int row = quad * 4 + 2 * s;
            bufH2[ row      * STRH + nt * 16 + c16] = h;
            bufH2[(row + 1) * STRH + nt * 16 + c16] = f2bf(v - bf2f(h));
          }
        }
        __syncthreads();                               // [C]

        // -------- layer 3 + contraction (OWN h-half only):
        // wave owns ntiles hb*128 + wv*8 .. +7  -> h = hb*64 + wv*4 .. +3
        {
          short8 a[8];
          #pragma unroll
          for (int kt = 0; kt < 8; ++kt)
            a[kt] = *(const short8*)&bufH2[c16 * STRH + kt * 32 + quad * 8];

          const int ntbase = hb * 128 + wv * 8;
          #pragma unroll 1
          for (int j = 0; j < 8; j += 2){
            float t0[2], t1[2];
            { // tile j: i in [0,16)
              const int nt = ntbase + j;
              const unsigned short* wp = w3p + ((long)(nt * 8) << 9) + lane * 8;
              short8 b[8];
              #pragma unroll
              for (int kt = 0; kt < 8; ++kt) b[kt] = *(const short8*)(wp + (kt << 9));
              float4v acc = { 0.f, 0.f, 0.f, 0.f };
              #pragma unroll
              for (int kt = 0; kt < 8; ++kt)
                acc = __builtin_amdgcn_mfma_f32_16x16x32_bf16(a[kt], b[kt], acc, 0, 0, 0);
              const float bv = biasl[512 + nt * 16 + c16];
              #pragma unroll
              for (int s = 0; s < 2; ++s)
                t0[s] = tanh_f(acc[2 * s] + acc[2 * s + 1] + bv) * dd[0][s];
            }
            { // tile j+1: i in [16,32) + reduce + vf write
              const int nt = ntbase + j + 1;
              const unsigned short* wp = w3p + ((long)(nt * 8) << 9) + lane * 8;
              short8 b[8];
              #pragma unroll
              for (int kt = 0; kt < 8; ++kt) b[kt] = *(const short8*)(wp + (kt << 9));
              float4v acc = { 0.f, 0.f, 0.f, 0.f };
              #pragma unroll
              for (int kt = 0; kt < 8; ++kt)
                acc = __builtin_amdgcn_mfma_f32_16x16x32_bf16(a[kt], b[kt], acc, 0, 0, 0);
              const float bv = biasl[512 + nt * 16 + c16];
              #pragma unroll
              for (int s = 0; s < 2; ++s)
                t1[s] = tanh_f(acc[2 * s] + acc[2 * s + 1] + bv) * dd[1][s];
              const int hidx = (ntbase + j) >> 1;      // global h index (own half)
              #pragma unroll
              for (int s = 0; s < 2; ++s){
                float r = row_sum16(t0[s] + t1[s]);
                if (c16 == 15) vfs[(quad * 2 + s) * STRV + hidx] = r;
              }
            }
          }
        }
        __syncthreads();                               // [D] own-half vfs ready

        // -------- RK4 combine (own half) + publish; receive partner half
        if (own){
          const float k = vfs[zm * STRV + zd];
          float nin;
          if (st == 0){
            zacc = z + (hs * (1.f / 6.f)) * k;
            nin  = z + 0.5f * hs * k;
          } else if (st == 1){
            zacc += (hs * (1.f / 3.f)) * k;
            nin   = z + 0.5f * hs * k;
          } else if (st == 2){
            zacc += (hs * (1.f / 3.f)) * k;
            nin   = z + hs * k;
          } else {
            z    = zacc + (hs * (1.f / 6.f)) * k;
            nin  = z;
          }
          __hip_atomic_store((int*)&g_zx[((par * 64 + grp) * 2 + hb) * 512 + xidx],
                             __float_as_int(nin),
                             __ATOMIC_RELAXED, __HIP_MEMORY_SCOPE_AGENT);
          unsigned short h = f2bf(nin);
          bufZ[(2 * zm    ) * STRZ + zd] = h;
          bufZ[(2 * zm + 1) * STRZ + zd] = f2bf(nin - bf2f(h));
        }
        __syncthreads();                               // [E] drains publish stores
        if (tid == 0){
          __hip_atomic_store(&g_flag[blockIdx.x], stg,
                             __ATOMIC_RELEASE, __HIP_MEMORY_SCOPE_AGENT);
          while (__hip_atomic_load(&g_flag[prt],
                                   __ATOMIC_ACQUIRE, __HIP_MEMORY_SCOPE_AGENT) < stg)
            __builtin_amdgcn_s_sleep(2);
        }
        __syncthreads();                               // [F] partner slice visible
        if (!own){
          int u = __hip_atomic_load(
                    (const int*)&g_zx[((par * 64 + grp) * 2 + (1 - hb)) * 512 + xidx],
                    __ATOMIC_RELAXED, __HIP_MEMORY_SCOPE_AGENT);
          float v = __int_as_float(u);
          unsigned short h = f2bf(v);
          bufZ[(2 * zm    ) * STRZ + zd] = h;
          bufZ[(2 * zm + 1) * STRZ + zd] = f2bf(v - bf2f(h));
        }
      } // st
    } // sub

    __syncthreads();                                   // bufZ holds z(t[ti+1])
    // -------- decoder (both halves compute identical values; benign dup writes)
    if (wv < 8){
      short8 a[4];
      #pragma unroll
      for (int kt = 0; kt < 4; ++kt)
        a[kt] = *(const short8*)&bufZ[c16 * STRZ + kt * 32 + quad * 8];
      const int  nt    = wv & 3;
      const bool isStd = wv >= 4;
      const unsigned short* wp = (isStd ? swp : mwp) + ((long)(nt * 4) << 9) + lane * 8;
      short8 b[4];
      #pragma unroll
      for (int kt = 0; kt < 4; ++kt) b[kt] = *(const short8*)(wp + (kt << 9));
      float4v acc = { 0.f, 0.f, 0.f, 0.f };
      #pragma unroll
      for (int kt = 0; kt < 4; ++kt)
        acc = __builtin_amdgcn_mfma_f32_16x16x32_bf16(a[kt], b[kt], acc, 0, 0, 0);
      const float bv    = biasl[(isStd ? 4672 : 4608) + nt * 16 + c16];
      const long  obase = isStd ? 8388608L : 0L;       // B*(T-1)*OUT
      #pragma unroll
      for (int s = 0; s < 2; ++s){
        float v = acc[2 * s] + acc[2 * s + 1] + bv;
        if (isStd) v = softplus_f(v);
        long oi = obase + ((long)(m0 + quad * 2 + s) * 256 + ti) * 64 + nt * 16 + c16;
        if constexpr (BF16) ((unsigned short*)outv)[oi] = f2bf(v);
        else                ((float*)outv)[oi] = v;
      }
    }
  } // ti
}

extern "C" void kernel_launch(void* const* d_in, const int* in_sizes, int n_in,
                              void* d_out, int out_size, void* d_ws, size_t ws_size,
                              hipStream_t stream)
{
  const void* t  = d_in[0];
  const void* z0 = d_in[1];
  const void* X  = d_in[2];
  const void* W1 = d_in[3];
  const void* b1 = d_in[4];
  const void* W2 = d_in[5];
  const void* b2 = d_in[6];
  const void* W3 = d_in[7];
  const void* b3 = d_in[8];
  const void* mW = d_in[9];
  const void* mb = d_in[10];
  const void* sW = d_in[11];
  const void* sb = d_in[12];

  // Both dtype variants launched; each checks input dtype and the
  // non-matching one returns immediately (t[0]==0.0 discriminator).
  pack_weight<true ><<<256, 256, 0, stream>>>(W1, 0, 128,  256, t);
  pack_weight<true ><<<256, 256, 0, stream>>>(W2, 1, 256,  256, t);
  pack_weight<true ><<<512, 256, 0, stream>>>(W3, 2, 256, 4096, t);
  pack_weight<true ><<< 64, 256, 0, stream>>>(mW, 3, 128,   64, t);
  pack_weight<true ><<< 64, 256, 0, stream>>>(sW, 4, 128,   64, t);
  pack_weight<false><<<256, 256, 0, stream>>>(W1, 0, 128,  256, t);
  pack_weight<false><<<256, 256, 0, stream>>>(W2, 1, 256,  256, t);
  pack_weight<false><<<512, 256, 0, stream>>>(W3, 2, 256, 4096, t);
  pack_weight<false><<< 64, 256, 0, stream>>>(mW, 3, 128,   64, t);
  pack_weight<false><<< 64, 256, 0, stream>>>(sW, 4, 128,   64, t);

  reset_flags<<<1, 128, 0, stream>>>();               // stream-ordered before main

  cde_main<true ><<<128, 1024, 0, stream>>>(t, z0, X, b1, b2, b3, mb, sb, d_out);
  cde_main<false><<<128, 1024, 0, stream>>>(t, z0, X, b1, b2, b3, mb, sb, d_out);
  (void)in_sizes; (void)n_in; (void)out_size; (void)d_ws; (void)ws_size;
}